// Round 8
// baseline (258.147 us; speedup 1.0000x reference)
//
#include <hip/hip_runtime.h>

#define NUM_CLASSES 6
#define NUM_SUBJECTS 16
#define NUM_PAIRS (NUM_CLASSES * NUM_SUBJECTS)   // 96
#define MARGIN 1.0f
#define EPS 1e-6f
#define INF_I 0x7fffffff

typedef _Float16 h2_t __attribute__((ext_vector_type(2)));

// ---------------- ws layout (bytes) ----------------
// [0)      int   min1[96]
// [384)    int   min2[96]
// [768)    int   cntPos[96]
// [1152)   int   cntSbj[16]
// [1216)   u64   best[96]        packed (sortable_f32(e2-2dot)<<32)|idx
// [1984)   int   done            last-block counter
// [2048)   u64   ancT[16*385]    prepacked swizzled f16 anchors (49280 B)

__device__ __forceinline__ unsigned int fkey(float f) {
    unsigned int b = __float_as_uint(f);
    return (b & 0x80000000u) ? ~b : (b | 0x80000000u);
}

__device__ __forceinline__ h2_t pk16(float x, float y) {
    return __builtin_bit_cast(h2_t, __builtin_amdgcn_cvt_pkrtz(x, y));
}

// one u64 = 4 f16 anchor dims; dot with f16x4 of the sample (2 fdot2)
__device__ __forceinline__ float dot4(unsigned long long A, h2_t vlo, h2_t vhi, float acc) {
#if __has_builtin(__builtin_amdgcn_fdot2)
    acc = __builtin_amdgcn_fdot2(__builtin_bit_cast(h2_t, (unsigned int)A), vlo, acc, false);
    acc = __builtin_amdgcn_fdot2(__builtin_bit_cast(h2_t, (unsigned int)(A >> 32)), vhi, acc, false);
#else
    h2_t a = __builtin_bit_cast(h2_t, (unsigned int)A);
    h2_t b = __builtin_bit_cast(h2_t, (unsigned int)(A >> 32));
    acc = fmaf((float)a.x, (float)vlo.x, fmaf((float)a.y, (float)vlo.y,
          fmaf((float)b.x, (float)vhi.x, fmaf((float)b.y, (float)vhi.y, acc))));
#endif
    return acc;
}

__global__ void k_init(int* min1, int* min2, int* cntPos, int* cntSbj,
                       unsigned long long* best, int* done) {
    int t = threadIdx.x;
    if (t < NUM_PAIRS) {
        min1[t] = INF_I;
        min2[t] = INF_I;
        cntPos[t] = 0;
        best[t] = ~0ull;
    }
    if (t < NUM_SUBJECTS) cntSbj[t] = 0;
    if (t == 127) *done = 0;
}

// Fused: first-two-positive mining + counts, single pass.
// Lock-free two-min: o = atomicMin(min1, i); atomicMin(min2, max(o, i)).
__global__ __launch_bounds__(1024) void k_stats(const int* __restrict__ labels,
                                                const int* __restrict__ sbj,
                                                int* min1, int* min2, int* cntPos,
                                                int* cntSbj, int B) {
    __shared__ int l1[NUM_PAIRS], l2[NUM_PAIRS], lcp[NUM_PAIRS], lcs[NUM_SUBJECTS];
    for (int t = threadIdx.x; t < NUM_PAIRS; t += blockDim.x) { l1[t] = INF_I; l2[t] = INF_I; lcp[t] = 0; }
    if (threadIdx.x < NUM_SUBJECTS) lcs[threadIdx.x] = 0;
    __syncthreads();
    for (int i = blockIdx.x * blockDim.x + threadIdx.x; i < B; i += gridDim.x * blockDim.x) {
        int s = sbj[i], c = labels[i];
        int p = s * NUM_CLASSES + c;
        int o = atomicMin(&l1[p], i);
        atomicMin(&l2[p], max(o, i));   // max(INF,i)=INF -> no-op on first insert
        atomicAdd(&lcp[p], 1);
        atomicAdd(&lcs[s], 1);
    }
    __syncthreads();
    for (int t = threadIdx.x; t < NUM_PAIRS; t += blockDim.x) {
        int m1 = l1[t];
        if (m1 != INF_I) {
            int o = atomicMin(&min1[t], m1);
            atomicMin(&min2[t], max(o, m1));
            if (l2[t] != INF_I) atomicMin(&min2[t], l2[t]);
            atomicAdd(&cntPos[t], lcp[t]);
        }
    }
    if (threadIdx.x < NUM_SUBJECTS && lcs[threadIdx.x]) atomicAdd(&cntSbj[threadIdx.x], lcs[threadIdx.x]);
}

// Gather anchors and prepack as f16x4 u64 with the transpose-swizzle the mine
// kernel reads: for (q = f4-subindex 0..15, k = f4-step 0..3):
//   u64 idx within (s,c) 64-u64 block = ((2q + (k>>1)) ^ (q>>2))*2 + (k&1)
// (p ^ (p>>3) on pair index: bijective; read side = two aligned b128 per class
// with <=2-way banks). Subject stride 385 u64 decorrelates samples.
__global__ void k_gather(const float4* __restrict__ emb4, const int* __restrict__ min1,
                         unsigned long long* ancT, int B) {
    int pr = blockIdx.x;         // 0..95 = s*6+c
    int l = threadIdx.x;         // 0..63, f4 index = q + 16k
    int idx = min1[pr];
    if (idx < 0 || idx >= B) idx = 0;
    float4 v = emb4[(size_t)idx * 64 + l];
    unsigned int lou = __builtin_bit_cast(unsigned int, pk16(v.x, v.y));
    unsigned int hiu = __builtin_bit_cast(unsigned int, pk16(v.z, v.w));
    unsigned long long u = (unsigned long long)lou | ((unsigned long long)hiu << 32);
    int s = pr / NUM_CLASSES, c = pr - s * NUM_CLASSES;
    int q = l & 15, k = l >> 4;
    int sw = ((2 * q + (k >> 1)) ^ (q >> 2)) * 2 + (k & 1);
    ancT[s * 385 + c * 64 + sw] = u;
}

// Coalesced streaming mine + fused finalize.
// 16 lanes/sample, 4 samples/wave; per k-step one sample's 16 lanes read a
// contiguous 256 B chunk (16 full cache lines per wave instruction).
// Anchors: prepacked swizzled f16 table, staged by linear memcpy; per class
// two aligned ds_read_b128. Key omits |a|^2 (per-pair constant).
__global__ __launch_bounds__(512, 4) void k_mine(const float4* __restrict__ emb4,
                                                 const int* __restrict__ labels,
                                                 const int* __restrict__ sbj,
                                                 const unsigned long long* __restrict__ ancT,
                                                 unsigned long long* gbest,
                                                 const int* __restrict__ min1,
                                                 const int* __restrict__ min2,
                                                 const int* __restrict__ cntPos,
                                                 const int* __restrict__ cntSbj,
                                                 int* done, float* out, int B) {
    __shared__ __align__(16) unsigned long long ancB[NUM_SUBJECTS * 385];  // 49280 B
    __shared__ unsigned long long lbest[NUM_PAIRS];
    __shared__ float vals[NUM_PAIRS];
    __shared__ int vld[NUM_PAIRS];
    __shared__ int lastFlag;

    // stage: straight 16 B memcpy of the prepacked table (L2-hot, 48 KB)
    {
        const ulonglong2* src = (const ulonglong2*)ancT;
        ulonglong2* dst = (ulonglong2*)ancB;
        for (int u = threadIdx.x; u < NUM_SUBJECTS * 385 / 2; u += blockDim.x) dst[u] = src[u];
    }
    for (int t = threadIdx.x; t < NUM_PAIRS; t += blockDim.x) lbest[t] = ~0ull;
    __syncthreads();

    const int lane = threadIdx.x & 63;
    const int q = lane & 15;
    const int sloc = lane >> 4;
    const int wv = (int)(threadIdx.x >> 6);
    const int waveGlob = (int)blockIdx.x * 8 + wv;
    const int nwv = (int)gridDim.x * 8;
    const int p0 = ((2 * q) ^ (q >> 2)) * 2;        // u64 offset of k=0,1 pair
    const int p1 = ((2 * q + 1) ^ (q >> 2)) * 2;    // u64 offset of k=2,3 pair

    for (int base = waveGlob * 4; base < B; base += nwv * 4) {
        int row = base + sloc;
        bool valid = row < B;
        int ic = valid ? row : (B - 1);
        int s = sbj[ic];
        int lbl = labels[ic];
        const float4* rp = emb4 + (size_t)ic * 64 + q;
        float4 v0 = rp[0], v1 = rp[16], v2 = rp[32], v3 = rp[48];

        float e2 = 0.f;
        e2 = fmaf(v0.x, v0.x, fmaf(v0.y, v0.y, fmaf(v0.z, v0.z, fmaf(v0.w, v0.w, e2))));
        e2 = fmaf(v1.x, v1.x, fmaf(v1.y, v1.y, fmaf(v1.z, v1.z, fmaf(v1.w, v1.w, e2))));
        e2 = fmaf(v2.x, v2.x, fmaf(v2.y, v2.y, fmaf(v2.z, v2.z, fmaf(v2.w, v2.w, e2))));
        e2 = fmaf(v3.x, v3.x, fmaf(v3.y, v3.y, fmaf(v3.z, v3.z, fmaf(v3.w, v3.w, e2))));

        h2_t vl0 = pk16(v0.x, v0.y), vh0 = pk16(v0.z, v0.w);
        h2_t vl1 = pk16(v1.x, v1.y), vh1 = pk16(v1.z, v1.w);
        h2_t vl2 = pk16(v2.x, v2.y), vh2 = pk16(v2.z, v2.w);
        h2_t vl3 = pk16(v3.x, v3.y), vh3 = pk16(v3.z, v3.w);

        const unsigned long long* anc = ancB + s * 385;
        float d[NUM_CLASSES];
#pragma unroll
        for (int c = 0; c < NUM_CLASSES; ++c) {
            const unsigned long long* ab = anc + c * 64;
            ulonglong2 A01 = *(const ulonglong2*)(ab + p0);
            ulonglong2 A23 = *(const ulonglong2*)(ab + p1);
            float acc = 0.f;
            acc = dot4(A01.x, vl0, vh0, acc);
            acc = dot4(A01.y, vl1, vh1, acc);
            acc = dot4(A23.x, vl2, vh2, acc);
            acc = dot4(A23.y, vl3, vh3, acc);
            d[c] = acc;
        }
        // reduce over the 16 q-lanes (butterfly)
#pragma unroll
        for (int m = 1; m <= 8; m <<= 1) {
            e2 += __shfl_xor(e2, m, 64);
#pragma unroll
            for (int c = 0; c < NUM_CLASSES; ++c) d[c] += __shfl_xor(d[c], m, 64);
        }

        if (valid && q == 0) {
            int pb = s * NUM_CLASSES;
#pragma unroll
            for (int c = 0; c < NUM_CLASSES; ++c) {
                if (c != lbl) {
                    float kd = e2 - 2.f * d[c];   // d^2 minus per-pair const |a|^2
                    unsigned long long pk =
                        ((unsigned long long)fkey(kd) << 32) | (unsigned int)row;
                    atomicMin(&lbest[pb + c], pk);
                }
            }
        }
    }
    __syncthreads();
    for (int t = threadIdx.x; t < NUM_PAIRS; t += blockDim.x) {
        unsigned long long v = lbest[t];
        if (v != ~0ull) {
            unsigned long long cur = gbest[t];   // racy monotone filter
            if (v < cur) atomicMin(&gbest[t], v);
        }
    }
    __threadfence();
    if (threadIdx.x == 0) {
        int old = atomicAdd(done, 1);
        lastFlag = (old == (int)gridDim.x - 1);
    }
    __syncthreads();
    if (!lastFlag) return;
    __threadfence();   // acquire: all blocks' gbest updates visible

    // ---- fused finalize (one block, 8 waves) ----
    int wave = threadIdx.x >> 6;
    int flane = threadIdx.x & 63;
    for (int p = wave; p < NUM_PAIRS; p += 8) {
        int s = p / NUM_CLASSES;
        int ai = min1[p], pi = min2[p];
        int npos = cntPos[p];
        int nneg = cntSbj[s] - npos;
        unsigned long long bb = atomicMin(&gbest[p], ~0ull);  // atomic read (no-op write)
        int ni = (int)(bb & 0xffffffffu);
        bool ok = (npos >= 2) && (nneg >= 1) && (bb != ~0ull);
        if (ai < 0 || ai >= B) ai = 0;
        if (pi < 0 || pi >= B) pi = 0;
        if (ni < 0 || ni >= B) ni = 0;
        float4 a = emb4[(size_t)ai * 64 + flane];
        float4 pp = emb4[(size_t)pi * 64 + flane];
        float4 nn = emb4[(size_t)ni * 64 + flane];
        float dap = 0.f, dan = 0.f, t;
        t = a.x - pp.x + EPS; dap += t * t;
        t = a.y - pp.y + EPS; dap += t * t;
        t = a.z - pp.z + EPS; dap += t * t;
        t = a.w - pp.w + EPS; dap += t * t;
        t = a.x - nn.x + EPS; dan += t * t;
        t = a.y - nn.y + EPS; dan += t * t;
        t = a.z - nn.z + EPS; dan += t * t;
        t = a.w - nn.w + EPS; dan += t * t;
#pragma unroll
        for (int m = 32; m >= 1; m >>= 1) {
            dap += __shfl_xor(dap, m, 64);
            dan += __shfl_xor(dan, m, 64);
        }
        if (flane == 0) {
            float lv = sqrtf(dap) - sqrtf(dan) + MARGIN;
            vals[p] = ok ? fmaxf(lv, 0.f) : 0.f;
            vld[p] = ok ? 1 : 0;
        }
    }
    __syncthreads();
    if (threadIdx.x == 0) {
        float sum = 0.f;
        int cnt = 0;
        for (int p = 0; p < NUM_PAIRS; ++p) { sum += vals[p]; cnt += vld[p]; }
        out[0] = (cnt > 0) ? (sum / (float)cnt) : 0.f;
    }
}

extern "C" void kernel_launch(void* const* d_in, const int* in_sizes, int n_in,
                              void* d_out, int out_size, void* d_ws, size_t ws_size,
                              hipStream_t stream) {
    const float* emb = (const float*)d_in[0];
    const int* labels = (const int*)d_in[1];
    const int* sbj = (const int*)d_in[2];
    float* out = (float*)d_out;
    const int B = in_sizes[1];           // 131072
    const float4* emb4 = (const float4*)emb;

    char* ws = (char*)d_ws;
    int* min1 = (int*)(ws + 0);
    int* min2 = (int*)(ws + 384);
    int* cntPos = (int*)(ws + 768);
    int* cntSbj = (int*)(ws + 1152);
    unsigned long long* best = (unsigned long long*)(ws + 1216);
    int* done = (int*)(ws + 1984);
    unsigned long long* ancT = (unsigned long long*)(ws + 2048);

    k_init<<<1, 128, 0, stream>>>(min1, min2, cntPos, cntSbj, best, done);

    k_stats<<<128, 1024, 0, stream>>>(labels, sbj, min1, min2, cntPos, cntSbj, B);

    k_gather<<<NUM_PAIRS, 64, 0, stream>>>(emb4, min1, ancT, B);

    // 1024 blocks x 8 waves x 4 samples x 4 rounds = 131072 exactly
    k_mine<<<1024, 512, 0, stream>>>(emb4, labels, sbj, ancT, best,
                                     min1, min2, cntPos, cntSbj, done, out, B);
}

// Round 9
// 97.191 us; speedup vs baseline: 2.6561x; 2.6561x over previous
//
#include <hip/hip_runtime.h>

#define NUM_CLASSES 6
#define NUM_SUBJECTS 16
#define NUM_PAIRS (NUM_CLASSES * NUM_SUBJECTS)   // 96
#define MARGIN 1.0f
#define EPS 1e-6f
#define INF_I 0x7fffffff

typedef _Float16 h2_t __attribute__((ext_vector_type(2)));

// ---------------- ws layout (bytes) ----------------
// [0)      int   min1[96]
// [384)    int   min2[96]
// [768)    int   cntPos[96]
// [1152)   int   cntSbj[16]
// [1216)   u64   best[96]        packed (sortable_f32(e2-2dot)<<32)|idx
// [1984)   int   done            last-block counter

__device__ __forceinline__ unsigned int fkey(float f) {
    unsigned int b = __float_as_uint(f);
    return (b & 0x80000000u) ? ~b : (b | 0x80000000u);
}

__device__ __forceinline__ h2_t pk16(float x, float y) {
    return __builtin_bit_cast(h2_t, __builtin_amdgcn_cvt_pkrtz(x, y));
}

// one u64 = 4 f16 anchor dims; dot with f16x4 of the sample (2 fdot2)
__device__ __forceinline__ float dot4(unsigned long long A, h2_t vlo, h2_t vhi, float acc) {
#if __has_builtin(__builtin_amdgcn_fdot2)
    acc = __builtin_amdgcn_fdot2(__builtin_bit_cast(h2_t, (unsigned int)A), vlo, acc, false);
    acc = __builtin_amdgcn_fdot2(__builtin_bit_cast(h2_t, (unsigned int)(A >> 32)), vhi, acc, false);
#else
    h2_t a = __builtin_bit_cast(h2_t, (unsigned int)A);
    h2_t b = __builtin_bit_cast(h2_t, (unsigned int)(A >> 32));
    acc = fmaf((float)a.x, (float)vlo.x, fmaf((float)a.y, (float)vlo.y,
          fmaf((float)b.x, (float)vhi.x, fmaf((float)b.y, (float)vhi.y, acc))));
#endif
    return acc;
}

__global__ void k_init(int* min1, int* min2, int* cntPos, int* cntSbj,
                       unsigned long long* best, int* done) {
    int t = threadIdx.x;
    if (t < NUM_PAIRS) {
        min1[t] = INF_I;
        min2[t] = INF_I;
        cntPos[t] = 0;
        best[t] = ~0ull;
    }
    if (t < NUM_SUBJECTS) cntSbj[t] = 0;
    if (t == 127) *done = 0;
}

// Fused: first-two-positive mining + counts, single pass.
// Lock-free two-min: o = atomicMin(min1, i); atomicMin(min2, max(o, i)).
__global__ __launch_bounds__(1024) void k_stats(const int* __restrict__ labels,
                                                const int* __restrict__ sbj,
                                                int* min1, int* min2, int* cntPos,
                                                int* cntSbj, int B) {
    __shared__ int l1[NUM_PAIRS], l2[NUM_PAIRS], lcp[NUM_PAIRS], lcs[NUM_SUBJECTS];
    for (int t = threadIdx.x; t < NUM_PAIRS; t += blockDim.x) { l1[t] = INF_I; l2[t] = INF_I; lcp[t] = 0; }
    if (threadIdx.x < NUM_SUBJECTS) lcs[threadIdx.x] = 0;
    __syncthreads();
    for (int i = blockIdx.x * blockDim.x + threadIdx.x; i < B; i += gridDim.x * blockDim.x) {
        int s = sbj[i], c = labels[i];
        int p = s * NUM_CLASSES + c;
        int o = atomicMin(&l1[p], i);
        atomicMin(&l2[p], max(o, i));   // max(INF,i)=INF -> no-op on first insert
        atomicAdd(&lcp[p], 1);
        atomicAdd(&lcs[s], 1);
    }
    __syncthreads();
    for (int t = threadIdx.x; t < NUM_PAIRS; t += blockDim.x) {
        int m1 = l1[t];
        if (m1 != INF_I) {
            int o = atomicMin(&min1[t], m1);
            atomicMin(&min2[t], max(o, m1));
            if (l2[t] != INF_I) atomicMin(&min2[t], l2[t]);
            atomicAdd(&cntPos[t], lcp[t]);
        }
    }
    if (threadIdx.x < NUM_SUBJECTS && lcs[threadIdx.x]) atomicAdd(&cntSbj[threadIdx.x], lcs[threadIdx.x]);
}

// Coalesced streaming mine + fused anchor-gather + fused finalize.
// 16 lanes/sample, 4 samples/wave; per k-step one sample's 16 lanes read a
// contiguous 256 B chunk (16 full cache lines per wave instruction).
// Anchors f16 in LDS, u64[s*385 + c*64 + k*16 + q] (round-7 proven layout:
// 16 consecutive u64 per ds_read group -> banks 0..31 exactly once).
// Cross-block: device-scope atomic RMWs only; ONE threadfence per block.
__global__ __launch_bounds__(512, 6) void k_mine(const float4* __restrict__ emb4,
                                                 const int* __restrict__ labels,
                                                 const int* __restrict__ sbj,
                                                 const int* __restrict__ min1,
                                                 const int* __restrict__ min2,
                                                 const int* __restrict__ cntPos,
                                                 const int* __restrict__ cntSbj,
                                                 unsigned long long* gbest,
                                                 int* done, float* out, int B) {
    __shared__ unsigned long long ancB[NUM_SUBJECTS * 385];   // 49280 B
    __shared__ unsigned long long lbest[NUM_PAIRS];
    __shared__ float vals[NUM_PAIRS];
    __shared__ int vld[NUM_PAIRS];
    __shared__ int lastFlag;

    // fused gather: stage 96 anchor rows from emb (L2-hot after first block)
    for (int u = threadIdx.x; u < NUM_PAIRS * 64; u += blockDim.x) {
        int pr = u >> 6;             // pair = s*6+c
        int l = u & 63;              // u64 index within row (= q + 16k)
        int idx = min1[pr];
        if (idx < 0 || idx >= B) idx = 0;
        float4 v = emb4[(size_t)idx * 64 + l];
        unsigned int lou = __builtin_bit_cast(unsigned int, pk16(v.x, v.y));
        unsigned int hiu = __builtin_bit_cast(unsigned int, pk16(v.z, v.w));
        int s = pr / NUM_CLASSES, c = pr - s * NUM_CLASSES;
        ancB[s * 385 + c * 64 + l] = (unsigned long long)lou | ((unsigned long long)hiu << 32);
    }
    for (int t = threadIdx.x; t < NUM_PAIRS; t += blockDim.x) lbest[t] = ~0ull;
    __syncthreads();

    const int lane = threadIdx.x & 63;
    const int q = lane & 15;                        // float4 sub-index
    const int sloc = lane >> 4;                     // 0..3 sample-in-wave
    const int wv = (int)(threadIdx.x >> 6);         // 0..7
    const int waveGlob = (int)blockIdx.x * 8 + wv;
    const int nwv = (int)gridDim.x * 8;

    for (int base = waveGlob * 4; base < B; base += nwv * 4) {
        int row = base + sloc;
        bool valid = row < B;
        int ic = valid ? row : (B - 1);
        int s = sbj[ic];
        int lbl = labels[ic];
        const float4* rp = emb4 + (size_t)ic * 64 + q;
        const unsigned long long* anc = ancB + s * 385 + q;

        float e2 = 0.f, d0 = 0.f, d1 = 0.f, d2v = 0.f, d3 = 0.f, d4 = 0.f, d5 = 0.f;
#pragma unroll
        for (int k = 0; k < 4; ++k) {
            float4 v = rp[k * 16];
            e2 = fmaf(v.x, v.x, fmaf(v.y, v.y, fmaf(v.z, v.z, fmaf(v.w, v.w, e2))));
            h2_t vlo = pk16(v.x, v.y);
            h2_t vhi = pk16(v.z, v.w);
            d0  = dot4(anc[0 * 64 + k * 16], vlo, vhi, d0);
            d1  = dot4(anc[1 * 64 + k * 16], vlo, vhi, d1);
            d2v = dot4(anc[2 * 64 + k * 16], vlo, vhi, d2v);
            d3  = dot4(anc[3 * 64 + k * 16], vlo, vhi, d3);
            d4  = dot4(anc[4 * 64 + k * 16], vlo, vhi, d4);
            d5  = dot4(anc[5 * 64 + k * 16], vlo, vhi, d5);
        }
        // reduce over the 16 q-lanes (butterfly)
#pragma unroll
        for (int m = 1; m <= 8; m <<= 1) {
            e2  += __shfl_xor(e2, m, 64);
            d0  += __shfl_xor(d0, m, 64);
            d1  += __shfl_xor(d1, m, 64);
            d2v += __shfl_xor(d2v, m, 64);
            d3  += __shfl_xor(d3, m, 64);
            d4  += __shfl_xor(d4, m, 64);
            d5  += __shfl_xor(d5, m, 64);
        }

        if (valid && q == 0) {
            int pb = s * NUM_CLASSES;
            float dc[NUM_CLASSES] = {d0, d1, d2v, d3, d4, d5};
#pragma unroll
            for (int c = 0; c < NUM_CLASSES; ++c) {
                if (c != lbl) {
                    float kd = e2 - 2.f * dc[c];   // d^2 minus per-pair const |a|^2
                    unsigned long long pk =
                        ((unsigned long long)fkey(kd) << 32) | (unsigned int)row;
                    atomicMin(&lbest[pb + c], pk);
                }
            }
        }
    }
    __syncthreads();
    // flush: device-scope atomic RMWs (coherent at home L2 slice)
    for (int t = threadIdx.x; t < NUM_PAIRS; t += blockDim.x) {
        unsigned long long v = lbest[t];
        if (v != ~0ull) {
            unsigned long long cur = gbest[t];   // racy monotone filter (stale >= actual)
            if (v < cur) atomicMin(&gbest[t], v);
        }
    }
    __syncthreads();   // compiler drains vmcnt(0) per wave before the barrier
    if (threadIdx.x == 0) {
        __threadfence();                          // ONE per block (768 total)
        lastFlag = (atomicAdd(done, 1) == (int)gridDim.x - 1);
    }
    __syncthreads();
    if (!lastFlag) return;

    // ---- fused finalize (last block only, 8 waves) ----
    int wave = threadIdx.x >> 6;
    int flane = threadIdx.x & 63;
    for (int p = wave; p < NUM_PAIRS; p += 8) {
        int s = p / NUM_CLASSES;
        int ai = min1[p], pi = min2[p];
        int npos = cntPos[p];
        int nneg = cntSbj[s] - npos;
        unsigned long long bb = atomicMin(&gbest[p], ~0ull);  // coherent RMW read
        int ni = (int)(bb & 0xffffffffu);
        bool ok = (npos >= 2) && (nneg >= 1) && (bb != ~0ull);
        if (ai < 0 || ai >= B) ai = 0;
        if (pi < 0 || pi >= B) pi = 0;
        if (ni < 0 || ni >= B) ni = 0;
        float4 a = emb4[(size_t)ai * 64 + flane];
        float4 pp = emb4[(size_t)pi * 64 + flane];
        float4 nn = emb4[(size_t)ni * 64 + flane];
        float dap = 0.f, dan = 0.f, t;
        t = a.x - pp.x + EPS; dap += t * t;
        t = a.y - pp.y + EPS; dap += t * t;
        t = a.z - pp.z + EPS; dap += t * t;
        t = a.w - pp.w + EPS; dap += t * t;
        t = a.x - nn.x + EPS; dan += t * t;
        t = a.y - nn.y + EPS; dan += t * t;
        t = a.z - nn.z + EPS; dan += t * t;
        t = a.w - nn.w + EPS; dan += t * t;
#pragma unroll
        for (int m = 32; m >= 1; m >>= 1) {
            dap += __shfl_xor(dap, m, 64);
            dan += __shfl_xor(dan, m, 64);
        }
        if (flane == 0) {
            float lv = sqrtf(dap) - sqrtf(dan) + MARGIN;
            vals[p] = ok ? fmaxf(lv, 0.f) : 0.f;
            vld[p] = ok ? 1 : 0;
        }
    }
    __syncthreads();
    if (threadIdx.x == 0) {
        float sum = 0.f;
        int cnt = 0;
        for (int p = 0; p < NUM_PAIRS; ++p) { sum += vals[p]; cnt += vld[p]; }
        out[0] = (cnt > 0) ? (sum / (float)cnt) : 0.f;
    }
}

extern "C" void kernel_launch(void* const* d_in, const int* in_sizes, int n_in,
                              void* d_out, int out_size, void* d_ws, size_t ws_size,
                              hipStream_t stream) {
    const float* emb = (const float*)d_in[0];
    const int* labels = (const int*)d_in[1];
    const int* sbj = (const int*)d_in[2];
    float* out = (float*)d_out;
    const int B = in_sizes[1];           // 131072
    const float4* emb4 = (const float4*)emb;

    char* ws = (char*)d_ws;
    int* min1 = (int*)(ws + 0);
    int* min2 = (int*)(ws + 384);
    int* cntPos = (int*)(ws + 768);
    int* cntSbj = (int*)(ws + 1152);
    unsigned long long* best = (unsigned long long*)(ws + 1216);
    int* done = (int*)(ws + 1984);

    k_init<<<1, 128, 0, stream>>>(min1, min2, cntPos, cntSbj, best, done);

    k_stats<<<128, 1024, 0, stream>>>(labels, sbj, min1, min2, cntPos, cntSbj, B);

    // 768 blocks = 3/CU x 256 CU, all resident; 8 waves x 4 samples each
    k_mine<<<768, 512, 0, stream>>>(emb4, labels, sbj, min1, min2, cntPos, cntSbj,
                                    best, done, out, B);
}

// Round 11
// 88.500 us; speedup vs baseline: 2.9169x; 1.0982x over previous
//
#include <hip/hip_runtime.h>
#include <hip/hip_bf16.h>

#define NUM_CLASSES 6
#define NUM_SUBJECTS 16
#define NUM_PAIRS (NUM_CLASSES * NUM_SUBJECTS)   // 96
#define MARGIN 1.0f
#define EPS 1e-6f
#define INF_I 0x7fffffff

typedef float f32x4 __attribute__((ext_vector_type(4)));
typedef short s16x8 __attribute__((ext_vector_type(8)));

// ---------------- ws layout (bytes) ----------------
// [0)      int   min1[96]
// [384)    int   min2[96]
// [768)    int   cntPos[96]
// [1152)   int   cntSbj[16]
// [1216)   u64   best[96]        packed (sortable_f32(e2-2dot)<<32)|idx
// [2048)   u64   ancT[96*64]     bf16 anchors, linear [pair][256] (49152 B)

__device__ __forceinline__ unsigned int fkey(float f) {
    unsigned int b = __float_as_uint(f);
    return (b & 0x80000000u) ? ~b : (b | 0x80000000u);
}

__device__ __forceinline__ unsigned int pkbf(float x, float y) {
    unsigned short a = __builtin_bit_cast(unsigned short, __float2bfloat16(x));
    unsigned short b = __builtin_bit_cast(unsigned short, __float2bfloat16(y));
    return (unsigned int)a | ((unsigned int)b << 16);
}

__global__ void k_init(int* min1, int* min2, int* cntPos, int* cntSbj,
                       unsigned long long* best) {
    int t = threadIdx.x;
    if (t < NUM_PAIRS) {
        min1[t] = INF_I;
        min2[t] = INF_I;
        cntPos[t] = 0;
        best[t] = ~0ull;
    }
    if (t < NUM_SUBJECTS) cntSbj[t] = 0;
}

// Fused: first-two-positive mining + counts, single pass.
__global__ __launch_bounds__(1024) void k_stats(const int* __restrict__ labels,
                                                const int* __restrict__ sbj,
                                                int* min1, int* min2, int* cntPos,
                                                int* cntSbj, int B) {
    __shared__ int l1[NUM_PAIRS], l2[NUM_PAIRS], lcp[NUM_PAIRS], lcs[NUM_SUBJECTS];
    for (int t = threadIdx.x; t < NUM_PAIRS; t += blockDim.x) { l1[t] = INF_I; l2[t] = INF_I; lcp[t] = 0; }
    if (threadIdx.x < NUM_SUBJECTS) lcs[threadIdx.x] = 0;
    __syncthreads();
    for (int i = blockIdx.x * blockDim.x + threadIdx.x; i < B; i += gridDim.x * blockDim.x) {
        int s = sbj[i], c = labels[i];
        int p = s * NUM_CLASSES + c;
        int o = atomicMin(&l1[p], i);
        atomicMin(&l2[p], max(o, i));
        atomicAdd(&lcp[p], 1);
        atomicAdd(&lcs[s], 1);
    }
    __syncthreads();
    for (int t = threadIdx.x; t < NUM_PAIRS; t += blockDim.x) {
        int m1 = l1[t];
        if (m1 != INF_I) {
            int o = atomicMin(&min1[t], m1);
            atomicMin(&min2[t], max(o, m1));
            if (l2[t] != INF_I) atomicMin(&min2[t], l2[t]);
            atomicAdd(&cntPos[t], lcp[t]);
        }
    }
    if (threadIdx.x < NUM_SUBJECTS && lcs[threadIdx.x]) atomicAdd(&cntSbj[threadIdx.x], lcs[threadIdx.x]);
}

// Gather 96 anchor rows, convert to bf16, store linear [pair][256] as u64x64.
__global__ void k_gather(const float4* __restrict__ emb4, const int* __restrict__ min1,
                         unsigned long long* ancT, int B) {
    int pr = blockIdx.x;         // 0..95
    int l = threadIdx.x;         // 0..63
    int idx = min1[pr];
    if (idx < 0 || idx >= B) idx = 0;
    float4 v = emb4[(size_t)idx * 64 + l];
    unsigned long long u = (unsigned long long)pkbf(v.x, v.y)
                         | ((unsigned long long)pkbf(v.z, v.w) << 32);
    ancT[pr * 64 + l] = u;
}

// MFMA mine: per block, 64 samples x 96 pairs x K=256 via 16x16x32 bf16.
// A-tile (emb rows, bf16) and B (anchors, 2 K-halves) in XOR-swizzled LDS
// (byte ^ ((row&7)<<4): uniform bank spread for b128 frag reads).
// C layout (m89-verified): col = lane&15 (pair), row = (lane>>4)*4 + reg.
// Epilogue: key = e2(exact f32) - 2*S, predicated LDS u64 atomicMin.
__global__ __launch_bounds__(256, 2) void k_mine(const float4* __restrict__ emb4,
                                                 const int* __restrict__ labels,
                                                 const int* __restrict__ sbj,
                                                 const unsigned long long* __restrict__ ancT,
                                                 unsigned long long* gbest, int B) {
    __shared__ __align__(16) char ldsA[64 * 512];    // 64 rows x 256 bf16 (32768 B)
    __shared__ __align__(16) char ldsB[96 * 256];    // 96 pairs x 128 bf16 half (24576 B)
    __shared__ float e2s[64];
    __shared__ int sbjT[64], lblT[64];
    __shared__ unsigned long long lbest[NUM_PAIRS];

    const int t = threadIdx.x;
    const int R0 = (int)blockIdx.x * 64;
    const int lane = t & 63;
    const int wv = t >> 6;                           // 0..3

    for (int u = t; u < NUM_PAIRS; u += blockDim.x) lbest[u] = ~0ull;

    // ---- stage A: 64 rows x 64 float4 = 4096 float4, 16 iters x 256 thr ----
    // iteration it: wave wv stages row (it*4 + wv), lane owns float4 #lane.
    // e2 per row: wave butterfly reduction (row is wave-uniform), lane0 stores.
#pragma unroll 4
    for (int it = 0; it < 16; ++it) {
        int fi = it * 256 + t;                       // float4 index in tile
        float4 v = emb4[(size_t)R0 * 64 + fi];
        int row = it * 4 + wv;                       // == fi >> 6
        float psq = fmaf(v.x, v.x, fmaf(v.y, v.y, fmaf(v.z, v.z, v.w * v.w)));
#pragma unroll
        for (int m = 32; m >= 1; m >>= 1) psq += __shfl_xor(psq, m, 64);
        if (lane == 0) e2s[row] = psq;
        unsigned long long u = (unsigned long long)pkbf(v.x, v.y)
                             | ((unsigned long long)pkbf(v.z, v.w) << 32);
        int off = (lane * 8) ^ ((row & 7) << 4);
        *(unsigned long long*)(ldsA + row * 512 + off) = u;
    }
    if (t < 64) { sbjT[t] = sbj[R0 + t]; lblT[t] = labels[R0 + t]; }
    // ---- stage B half 0 (anchors k 0..127; L2-hot 24 KB) ----
    {
        const ulonglong2* src = (const ulonglong2*)ancT;
#pragma unroll
        for (int it = 0; it < 6; ++it) {
            int u = it * 256 + t;                    // 1536 chunks of 16 B
            int pair = u >> 4, w = u & 15;
            ulonglong2 val = src[pair * 32 + w];
            *(ulonglong2*)(ldsB + pair * 256 + ((w * 16) ^ ((pair & 7) << 4))) = val;
        }
    }
    __syncthreads();

    f32x4 acc[6];
#pragma unroll
    for (int ct = 0; ct < 6; ++ct) acc[ct] = f32x4{0.f, 0.f, 0.f, 0.f};

    const int rloc = wv * 16 + (lane & 15);
    const int asw = (rloc & 7) << 4;
    const int col = lane & 15;
    const int kgrp = (lane >> 4) << 4;               // 0,16,32,48 bytes

#pragma unroll
    for (int kh = 0; kh < 2; ++kh) {
        if (kh == 1) {
            __syncthreads();                         // done reading B half 0
            const ulonglong2* src = (const ulonglong2*)ancT;
#pragma unroll
            for (int it = 0; it < 6; ++it) {
                int u = it * 256 + t;
                int pair = u >> 4, w = u & 15;
                ulonglong2 val = src[pair * 32 + 16 + w];
                *(ulonglong2*)(ldsB + pair * 256 + ((w * 16) ^ ((pair & 7) << 4))) = val;
            }
            __syncthreads();
        }
#pragma unroll
        for (int ksl = 0; ksl < 4; ++ksl) {
            int kb = ksl * 64 + kgrp;
            s16x8 a = *(const s16x8*)(ldsA + rloc * 512 + ((kh * 256 + kb) ^ asw));
#pragma unroll
            for (int ct = 0; ct < 6; ++ct) {
                int p = ct * 16 + col;
                s16x8 b = *(const s16x8*)(ldsB + p * 256 + (kb ^ ((p & 7) << 4)));
                acc[ct] = __builtin_amdgcn_mfma_f32_16x16x32_bf16(a, b, acc[ct], 0, 0, 0);
            }
        }
    }

    // ---- epilogue: key = e2 - 2*S, predicated atomicMin ----
    const int rb = wv * 16 + ((lane >> 4) << 2);     // this lane's 4 C rows
    float e2r[4]; int sr[4], lr[4];
#pragma unroll
    for (int r = 0; r < 4; ++r) { e2r[r] = e2s[rb + r]; sr[r] = sbjT[rb + r]; lr[r] = lblT[rb + r]; }
#pragma unroll
    for (int ct = 0; ct < 6; ++ct) {
        int p = ct * 16 + col;
        int sp = p / NUM_CLASSES, cp = p - sp * NUM_CLASSES;
#pragma unroll
        for (int r = 0; r < 4; ++r) {
            if (sr[r] == sp && lr[r] != cp) {
                float key = e2r[r] - 2.0f * acc[ct][r];
                unsigned long long pk =
                    ((unsigned long long)fkey(key) << 32) | (unsigned int)(R0 + rb + r);
                atomicMin(&lbest[p], pk);
            }
        }
    }
    __syncthreads();
    for (int u = t; u < NUM_PAIRS; u += blockDim.x) {
        unsigned long long v = lbest[u];
        if (v != ~0ull) {
            unsigned long long cur = gbest[u];       // racy monotone filter
            if (v < cur) atomicMin(&gbest[u], v);
        }
    }
}

__global__ __launch_bounds__(1024) void k_finalize(const float4* __restrict__ emb4,
                                                   const int* __restrict__ min1,
                                                   const int* __restrict__ min2,
                                                   const int* __restrict__ cntPos,
                                                   const int* __restrict__ cntSbj,
                                                   const unsigned long long* __restrict__ best,
                                                   float* out, int B) {
    __shared__ float vals[NUM_PAIRS];
    __shared__ int vld[NUM_PAIRS];
    int wave = threadIdx.x >> 6;
    int lane = threadIdx.x & 63;
    for (int p = wave; p < NUM_PAIRS; p += (blockDim.x >> 6)) {
        int s = p / NUM_CLASSES;
        int ai = min1[p], pi = min2[p];
        int npos = cntPos[p];
        int nneg = cntSbj[s] - npos;
        unsigned long long bb = best[p];
        int ni = (int)(bb & 0xffffffffu);
        bool ok = (npos >= 2) && (nneg >= 1) && (bb != ~0ull);
        if (ai < 0 || ai >= B) ai = 0;
        if (pi < 0 || pi >= B) pi = 0;
        if (ni < 0 || ni >= B) ni = 0;
        float4 a = emb4[(size_t)ai * 64 + lane];
        float4 pp = emb4[(size_t)pi * 64 + lane];
        float4 nn = emb4[(size_t)ni * 64 + lane];
        float dap = 0.f, dan = 0.f, tt;
        tt = a.x - pp.x + EPS; dap += tt * tt;
        tt = a.y - pp.y + EPS; dap += tt * tt;
        tt = a.z - pp.z + EPS; dap += tt * tt;
        tt = a.w - pp.w + EPS; dap += tt * tt;
        tt = a.x - nn.x + EPS; dan += tt * tt;
        tt = a.y - nn.y + EPS; dan += tt * tt;
        tt = a.z - nn.z + EPS; dan += tt * tt;
        tt = a.w - nn.w + EPS; dan += tt * tt;
#pragma unroll
        for (int m = 32; m >= 1; m >>= 1) {
            dap += __shfl_xor(dap, m, 64);
            dan += __shfl_xor(dan, m, 64);
        }
        if (lane == 0) {
            float lv = sqrtf(dap) - sqrtf(dan) + MARGIN;
            vals[p] = ok ? fmaxf(lv, 0.f) : 0.f;
            vld[p] = ok ? 1 : 0;
        }
    }
    __syncthreads();
    if (threadIdx.x == 0) {
        float sum = 0.f;
        int cnt = 0;
        for (int p = 0; p < NUM_PAIRS; ++p) { sum += vals[p]; cnt += vld[p]; }
        out[0] = (cnt > 0) ? (sum / (float)cnt) : 0.f;
    }
}

extern "C" void kernel_launch(void* const* d_in, const int* in_sizes, int n_in,
                              void* d_out, int out_size, void* d_ws, size_t ws_size,
                              hipStream_t stream) {
    const float* emb = (const float*)d_in[0];
    const int* labels = (const int*)d_in[1];
    const int* sbj = (const int*)d_in[2];
    float* out = (float*)d_out;
    const int B = in_sizes[1];           // 131072
    const float4* emb4 = (const float4*)emb;

    char* ws = (char*)d_ws;
    int* min1 = (int*)(ws + 0);
    int* min2 = (int*)(ws + 384);
    int* cntPos = (int*)(ws + 768);
    int* cntSbj = (int*)(ws + 1152);
    unsigned long long* best = (unsigned long long*)(ws + 1216);
    unsigned long long* ancT = (unsigned long long*)(ws + 2048);

    k_init<<<1, 128, 0, stream>>>(min1, min2, cntPos, cntSbj, best);

    k_stats<<<128, 1024, 0, stream>>>(labels, sbj, min1, min2, cntPos, cntSbj, B);

    k_gather<<<NUM_PAIRS, 64, 0, stream>>>(emb4, min1, ancT, B);

    k_mine<<<B / 64, 256, 0, stream>>>(emb4, labels, sbj, ancT, best, B);

    k_finalize<<<1, 1024, 0, stream>>>(emb4, min1, min2, cntPos, cntSbj, best, out, B);
}

// Round 12
// 66.287 us; speedup vs baseline: 3.8944x; 1.3351x over previous
//
#include <hip/hip_runtime.h>
#include <hip/hip_bf16.h>

#define NUM_CLASSES 6
#define NUM_SUBJECTS 16
#define NUM_PAIRS (NUM_CLASSES * NUM_SUBJECTS)   // 96
#define MARGIN 1.0f
#define EPS 1e-6f
#define INF_I 0x7fffffff

typedef float f32x4 __attribute__((ext_vector_type(4)));
typedef short s16x8 __attribute__((ext_vector_type(8)));

// ---------------- ws layout (bytes) ----------------
// [0)      int   min1[96]
// [384)    int   min2[96]
// [768)    int   cntPos[96]
// [1152)   int   cntSbj[16]
// [1216)   u64   best[96]        packed (sortable_f32(e2-2dot)<<32)|idx
// [2048)   u64   ancT[96*64]     bf16 anchors, linear [pair][256] (49152 B)

__device__ __forceinline__ unsigned int fkey(float f) {
    unsigned int b = __float_as_uint(f);
    return (b & 0x80000000u) ? ~b : (b | 0x80000000u);
}

__device__ __forceinline__ unsigned int pkbf(float x, float y) {
    unsigned short a = __builtin_bit_cast(unsigned short, __float2bfloat16(x));
    unsigned short b = __builtin_bit_cast(unsigned short, __float2bfloat16(y));
    return (unsigned int)a | ((unsigned int)b << 16);
}

__global__ void k_init(int* min1, int* min2, int* cntPos, int* cntSbj,
                       unsigned long long* best) {
    int t = threadIdx.x;
    if (t < NUM_PAIRS) {
        min1[t] = INF_I;
        min2[t] = INF_I;
        cntPos[t] = 0;
        best[t] = ~0ull;
    }
    if (t < NUM_SUBJECTS) cntSbj[t] = 0;
}

// Fused: first-two-positive mining + counts, single pass.
__global__ __launch_bounds__(1024) void k_stats(const int* __restrict__ labels,
                                                const int* __restrict__ sbj,
                                                int* min1, int* min2, int* cntPos,
                                                int* cntSbj, int B) {
    __shared__ int l1[NUM_PAIRS], l2[NUM_PAIRS], lcp[NUM_PAIRS], lcs[NUM_SUBJECTS];
    for (int t = threadIdx.x; t < NUM_PAIRS; t += blockDim.x) { l1[t] = INF_I; l2[t] = INF_I; lcp[t] = 0; }
    if (threadIdx.x < NUM_SUBJECTS) lcs[threadIdx.x] = 0;
    __syncthreads();
    for (int i = blockIdx.x * blockDim.x + threadIdx.x; i < B; i += gridDim.x * blockDim.x) {
        int s = sbj[i], c = labels[i];
        int p = s * NUM_CLASSES + c;
        int o = atomicMin(&l1[p], i);
        atomicMin(&l2[p], max(o, i));
        atomicAdd(&lcp[p], 1);
        atomicAdd(&lcs[s], 1);
    }
    __syncthreads();
    for (int t = threadIdx.x; t < NUM_PAIRS; t += blockDim.x) {
        int m1 = l1[t];
        if (m1 != INF_I) {
            int o = atomicMin(&min1[t], m1);
            atomicMin(&min2[t], max(o, m1));
            if (l2[t] != INF_I) atomicMin(&min2[t], l2[t]);
            atomicAdd(&cntPos[t], lcp[t]);
        }
    }
    if (threadIdx.x < NUM_SUBJECTS && lcs[threadIdx.x]) atomicAdd(&cntSbj[threadIdx.x], lcs[threadIdx.x]);
}

// Gather 96 anchor rows, convert to bf16, store linear [pair][256] as u64x64.
__global__ void k_gather(const float4* __restrict__ emb4, const int* __restrict__ min1,
                         unsigned long long* ancT, int B) {
    int pr = blockIdx.x;         // 0..95
    int l = threadIdx.x;         // 0..63
    int idx = min1[pr];
    if (idx < 0 || idx >= B) idx = 0;
    float4 v = emb4[(size_t)idx * 64 + l];
    unsigned long long u = (unsigned long long)pkbf(v.x, v.y)
                         | ((unsigned long long)pkbf(v.z, v.w) << 32);
    ancT[pr * 64 + l] = u;
}

// MFMA mine: per block (512 thr, 8 waves), 64 samples x 96 pairs x K=256.
// Wave task split: rt = wv&3 (16-row tile), ch = wv>>2 (48-pair col half).
// e2 via matrix unit: aG = mfma(a, a, aG) accumulates G = A_tile*A_tile^T;
// diag(G) = |row|^2 (bf16-rounded, key-precision only). No shuffles anywhere.
// A/B in XOR-swizzled LDS (byte ^ ((row&7)<<4)).
// C layout (m89): col = lane&15, row = (lane>>4)*4 + reg.
__global__ __launch_bounds__(512, 4) void k_mine(const float4* __restrict__ emb4,
                                                 const int* __restrict__ labels,
                                                 const int* __restrict__ sbj,
                                                 const unsigned long long* __restrict__ ancT,
                                                 unsigned long long* gbest, int B) {
    __shared__ __align__(16) char ldsA[64 * 512];    // 64 rows x 256 bf16 (32768 B)
    __shared__ __align__(16) char ldsB[96 * 256];    // 96 pairs x 128 bf16 half (24576 B)
    __shared__ float e2s[64];
    __shared__ int sbjT[64], lblT[64];
    __shared__ unsigned long long lbest[NUM_PAIRS];

    const int t = threadIdx.x;
    const int R0 = (int)blockIdx.x * 64;
    const int lane = t & 63;
    const int wv = t >> 6;                           // 0..7

    for (int u = t; u < NUM_PAIRS; u += blockDim.x) lbest[u] = ~0ull;

    // ---- stage A: 64 rows x 64 float4 = 4096 float4, 8 iters x 512 thr ----
#pragma unroll
    for (int it = 0; it < 8; ++it) {
        int fi = it * 512 + t;                       // float4 index in tile
        float4 v = emb4[(size_t)R0 * 64 + fi];
        int row = it * 8 + wv;                       // == fi >> 6
        unsigned long long u = (unsigned long long)pkbf(v.x, v.y)
                             | ((unsigned long long)pkbf(v.z, v.w) << 32);
        int off = (lane * 8) ^ ((row & 7) << 4);
        *(unsigned long long*)(ldsA + row * 512 + off) = u;
    }
    if (t < 64) { sbjT[t] = sbj[R0 + t]; lblT[t] = labels[R0 + t]; }
    // ---- stage B half 0 (anchors k 0..127; L2-hot 24 KB) ----
    {
        const ulonglong2* src = (const ulonglong2*)ancT;
#pragma unroll
        for (int it = 0; it < 3; ++it) {
            int u = it * 512 + t;                    // 1536 chunks of 16 B
            int pair = u >> 4, w = u & 15;
            ulonglong2 val = src[pair * 32 + w];
            *(ulonglong2*)(ldsB + pair * 256 + ((w * 16) ^ ((pair & 7) << 4))) = val;
        }
    }
    __syncthreads();

    const int rt = wv & 3;                           // row-tile 0..3
    const int ch = wv >> 2;                          // col half 0..1
    const int col = lane & 15;
    const int rloc = rt * 16 + col;                  // A-frag row
    const int asw = (col & 7) << 4;
    const int kgrp = (lane >> 4) << 4;               // 0,16,32,48 bytes

    f32x4 acc[3];
#pragma unroll
    for (int ct = 0; ct < 3; ++ct) acc[ct] = f32x4{0.f, 0.f, 0.f, 0.f};
    f32x4 aG = f32x4{0.f, 0.f, 0.f, 0.f};

#pragma unroll
    for (int kh = 0; kh < 2; ++kh) {
        if (kh == 1) {
            __syncthreads();                         // done reading B half 0
            const ulonglong2* src = (const ulonglong2*)ancT;
#pragma unroll
            for (int it = 0; it < 3; ++it) {
                int u = it * 512 + t;
                int pair = u >> 4, w = u & 15;
                ulonglong2 val = src[pair * 32 + 16 + w];
                *(ulonglong2*)(ldsB + pair * 256 + ((w * 16) ^ ((pair & 7) << 4))) = val;
            }
            __syncthreads();
        }
#pragma unroll
        for (int ksl = 0; ksl < 4; ++ksl) {
            int kb = ksl * 64 + kgrp;
            s16x8 a = *(const s16x8*)(ldsA + rloc * 512 + ((kh * 256 + kb) ^ asw));
            if (ch == 0)                             // G = A*A^T (e2 on diag)
                aG = __builtin_amdgcn_mfma_f32_16x16x32_bf16(a, a, aG, 0, 0, 0);
#pragma unroll
            for (int ct = 0; ct < 3; ++ct) {
                int p = (ch * 3 + ct) * 16 + col;
                s16x8 b = *(const s16x8*)(ldsB + p * 256 + (kb ^ ((p & 7) << 4)));
                acc[ct] = __builtin_amdgcn_mfma_f32_16x16x32_bf16(a, b, acc[ct], 0, 0, 0);
            }
        }
    }
    // diag(G): row == col -> lane>>4 == col>>2, reg = col&3
    if (ch == 0 && (lane >> 4) == (col >> 2)) e2s[rt * 16 + col] = aG[col & 3];
    __syncthreads();

    // ---- epilogue: key = e2 - 2*S, predicated LDS atomicMin ----
    const int rb = rt * 16 + ((lane >> 4) << 2);     // this lane's 4 C rows
    float e2r[4]; int sr[4], lr[4];
#pragma unroll
    for (int r = 0; r < 4; ++r) { e2r[r] = e2s[rb + r]; sr[r] = sbjT[rb + r]; lr[r] = lblT[rb + r]; }
#pragma unroll
    for (int ct = 0; ct < 3; ++ct) {
        int p = (ch * 3 + ct) * 16 + col;
        int sp = p / NUM_CLASSES, cp = p - sp * NUM_CLASSES;
#pragma unroll
        for (int r = 0; r < 4; ++r) {
            if (sr[r] == sp && lr[r] != cp) {
                float key = e2r[r] - 2.0f * acc[ct][r];
                unsigned long long pk =
                    ((unsigned long long)fkey(key) << 32) | (unsigned int)(R0 + rb + r);
                atomicMin(&lbest[p], pk);
            }
        }
    }
    __syncthreads();
    for (int u = t; u < NUM_PAIRS; u += blockDim.x) {
        unsigned long long v = lbest[u];
        if (v != ~0ull) {
            unsigned long long cur = gbest[u];       // racy monotone filter
            if (v < cur) atomicMin(&gbest[u], v);
        }
    }
}

__global__ __launch_bounds__(1024) void k_finalize(const float4* __restrict__ emb4,
                                                   const int* __restrict__ min1,
                                                   const int* __restrict__ min2,
                                                   const int* __restrict__ cntPos,
                                                   const int* __restrict__ cntSbj,
                                                   const unsigned long long* __restrict__ best,
                                                   float* out, int B) {
    __shared__ float vals[NUM_PAIRS];
    __shared__ int vld[NUM_PAIRS];
    int wave = threadIdx.x >> 6;
    int lane = threadIdx.x & 63;
    for (int p = wave; p < NUM_PAIRS; p += (blockDim.x >> 6)) {
        int s = p / NUM_CLASSES;
        int ai = min1[p], pi = min2[p];
        int npos = cntPos[p];
        int nneg = cntSbj[s] - npos;
        unsigned long long bb = best[p];
        int ni = (int)(bb & 0xffffffffu);
        bool ok = (npos >= 2) && (nneg >= 1) && (bb != ~0ull);
        if (ai < 0 || ai >= B) ai = 0;
        if (pi < 0 || pi >= B) pi = 0;
        if (ni < 0 || ni >= B) ni = 0;
        float4 a = emb4[(size_t)ai * 64 + lane];
        float4 pp = emb4[(size_t)pi * 64 + lane];
        float4 nn = emb4[(size_t)ni * 64 + lane];
        float dap = 0.f, dan = 0.f, tt;
        tt = a.x - pp.x + EPS; dap += tt * tt;
        tt = a.y - pp.y + EPS; dap += tt * tt;
        tt = a.z - pp.z + EPS; dap += tt * tt;
        tt = a.w - pp.w + EPS; dap += tt * tt;
        tt = a.x - nn.x + EPS; dan += tt * tt;
        tt = a.y - nn.y + EPS; dan += tt * tt;
        tt = a.z - nn.z + EPS; dan += tt * tt;
        tt = a.w - nn.w + EPS; dan += tt * tt;
#pragma unroll
        for (int m = 32; m >= 1; m >>= 1) {
            dap += __shfl_xor(dap, m, 64);
            dan += __shfl_xor(dan, m, 64);
        }
        if (lane == 0) {
            float lv = sqrtf(dap) - sqrtf(dan) + MARGIN;
            vals[p] = ok ? fmaxf(lv, 0.f) : 0.f;
            vld[p] = ok ? 1 : 0;
        }
    }
    __syncthreads();
    if (threadIdx.x == 0) {
        float sum = 0.f;
        int cnt = 0;
        for (int p = 0; p < NUM_PAIRS; ++p) { sum += vals[p]; cnt += vld[p]; }
        out[0] = (cnt > 0) ? (sum / (float)cnt) : 0.f;
    }
}

extern "C" void kernel_launch(void* const* d_in, const int* in_sizes, int n_in,
                              void* d_out, int out_size, void* d_ws, size_t ws_size,
                              hipStream_t stream) {
    const float* emb = (const float*)d_in[0];
    const int* labels = (const int*)d_in[1];
    const int* sbj = (const int*)d_in[2];
    float* out = (float*)d_out;
    const int B = in_sizes[1];           // 131072
    const float4* emb4 = (const float4*)emb;

    char* ws = (char*)d_ws;
    int* min1 = (int*)(ws + 0);
    int* min2 = (int*)(ws + 384);
    int* cntPos = (int*)(ws + 768);
    int* cntSbj = (int*)(ws + 1152);
    unsigned long long* best = (unsigned long long*)(ws + 1216);
    unsigned long long* ancT = (unsigned long long*)(ws + 2048);

    k_init<<<1, 128, 0, stream>>>(min1, min2, cntPos, cntSbj, best);

    k_stats<<<128, 1024, 0, stream>>>(labels, sbj, min1, min2, cntPos, cntSbj, B);

    k_gather<<<NUM_PAIRS, 64, 0, stream>>>(emb4, min1, ancT, B);

    k_mine<<<B / 64, 512, 0, stream>>>(emb4, labels, sbj, ancT, best, B);

    k_finalize<<<1, 1024, 0, stream>>>(emb4, min1, min2, cntPos, cntSbj, best, out, B);
}